// Round 1
// baseline (884.465 us; speedup 1.0000x reference)
//
#include <hip/hip_runtime.h>
#include <hip/hip_bf16.h>
#include <math.h>

#define N_FEAT 128
#define H1 64
#define H2 2

// ---------------------------------------------------------------------------
// Edge-index width detection: reference says int64, but JAX without x64 gives
// int32. Reading int32 pairs as u64 yields values >= 2^32 with overwhelming
// probability (values are < 100000). Uniform per-call, graph-capture safe.
// ---------------------------------------------------------------------------
__global__ void k_detect(const unsigned long long* __restrict__ E, int* __restrict__ flag) {
    if (threadIdx.x == 0 && blockIdx.x == 0) {
        int ok = 1;
        for (int i = 0; i < 16; ++i) {
            if (E[i] > 1000000ULL) { ok = 0; break; }
        }
        *flag = ok;  // 1 = int64, 0 = int32
    }
}

__device__ __forceinline__ int load_idx(const void* E, size_t i, int is64) {
    if (is64) return (int)((const long long*)E)[i];
    return ((const int*)E)[i];
}

// ---------------------------------------------------------------------------
// Histogram of dst (in-degree, excluding self loop)
// ---------------------------------------------------------------------------
__global__ void k_count(const void* __restrict__ E, size_t nE,
                        const int* __restrict__ flag, int* __restrict__ counts) {
    int is64 = *flag;
    size_t i = (size_t)blockIdx.x * blockDim.x + threadIdx.x;
    if (i < nE) {
        int d = load_idx(E, nE + i, is64);
        atomicAdd(&counts[d], 1);
    }
}

// ---------------------------------------------------------------------------
// Exclusive scan of counts -> rp (3-kernel: block scan, top scan, add)
// ---------------------------------------------------------------------------
__global__ void k_scan_block(const int* __restrict__ counts, int* __restrict__ rp,
                             int* __restrict__ bsum, int N) {
    int i = blockIdx.x * 256 + threadIdx.x;
    int c = (i < N) ? counts[i] : 0;
    int lane = threadIdx.x & 63, wv = threadIdx.x >> 6;
    int v = c;
#pragma unroll
    for (int off = 1; off < 64; off <<= 1) {
        int t = __shfl_up(v, off, 64);
        if (lane >= off) v += t;
    }
    __shared__ int wsums[4];
    if (lane == 63) wsums[wv] = v;
    __syncthreads();
    int add = 0;
    for (int w = 0; w < wv; ++w) add += wsums[w];
    int incl = v + add;
    if (i < N) rp[i] = incl - c;               // exclusive within block
    if (threadIdx.x == 255) bsum[blockIdx.x] = incl;
}

__global__ void k_scan_top(int* __restrict__ bsum, int nb) {
    __shared__ int s[512];
    int t = threadIdx.x;
    int own = (t < nb) ? bsum[t] : 0;
    s[t] = own;
    __syncthreads();
    for (int off = 1; off < 512; off <<= 1) {
        int v = (t >= off) ? s[t - off] : 0;
        __syncthreads();
        s[t] += v;
        __syncthreads();
    }
    if (t < nb) bsum[t] = s[t] - own;          // exclusive block offsets
}

__global__ void k_scan_add(int* __restrict__ rp, const int* __restrict__ bsum,
                           const int* __restrict__ counts, float* __restrict__ dinv,
                           int N, int nE) {
    int i = blockIdx.x * 256 + threadIdx.x;
    if (i < N) {
        rp[i] += bsum[i >> 8];
        dinv[i] = rsqrtf((float)(counts[i] + 1));   // +1 self loop; deg >= 1 always
    }
    if (i == 0 && blockIdx.x == 0) rp[N] = nE;
}

// ---------------------------------------------------------------------------
// CSR fill: col[pos] = src, grouped by dst
// ---------------------------------------------------------------------------
__global__ void k_fill(const void* __restrict__ E, size_t nE, const int* __restrict__ flag,
                       const int* __restrict__ rp, int* __restrict__ cur, int* __restrict__ col) {
    int is64 = *flag;
    size_t i = (size_t)blockIdx.x * blockDim.x + threadIdx.x;
    if (i < nE) {
        int s = load_idx(E, i, is64);
        int d = load_idx(E, nE + i, is64);
        int pos = rp[d] + atomicAdd(&cur[d], 1);
        col[pos] = s;
    }
}

// ---------------------------------------------------------------------------
// GEMM1: h1 = x @ W1   [N,128]@[128,64], fp32. W1 in LDS (32 KB).
// Wave-uniform x-row reads (scalar loads), coalesced h1 writes.
// ---------------------------------------------------------------------------
__global__ __launch_bounds__(256) void k_gemm1(const float* __restrict__ x,
                                               const float* __restrict__ W1,
                                               float* __restrict__ h1, int N) {
    __shared__ float Ws[N_FEAT * H1];
    for (int t = threadIdx.x; t < N_FEAT * H1; t += 256) Ws[t] = W1[t];
    __syncthreads();
    int lane = threadIdx.x & 63;
    int wv = threadIdx.x >> 6;
    int row0 = blockIdx.x * 16 + wv * 4;
    if (row0 >= N) return;
    // clamp reads (exact grid for N=100000, guard for safety)
    int r0 = row0, r1 = min(row0 + 1, N - 1), r2 = min(row0 + 2, N - 1), r3 = min(row0 + 3, N - 1);
    const float* x0 = x + (size_t)r0 * N_FEAT;
    const float* x1 = x + (size_t)r1 * N_FEAT;
    const float* x2 = x + (size_t)r2 * N_FEAT;
    const float* x3 = x + (size_t)r3 * N_FEAT;
    float a0 = 0.f, a1 = 0.f, a2 = 0.f, a3 = 0.f;
#pragma unroll 8
    for (int k = 0; k < N_FEAT; ++k) {
        float w = Ws[k * H1 + lane];
        a0 = fmaf(x0[k], w, a0);
        a1 = fmaf(x1[k], w, a1);
        a2 = fmaf(x2[k], w, a2);
        a3 = fmaf(x3[k], w, a3);
    }
    if (row0 + 0 < N) h1[(size_t)(row0 + 0) * H1 + lane] = a0;
    if (row0 + 1 < N) h1[(size_t)(row0 + 1) * H1 + lane] = a1;
    if (row0 + 2 < N) h1[(size_t)(row0 + 2) * H1 + lane] = a2;
    if (row0 + 3 < N) h1[(size_t)(row0 + 3) * H1 + lane] = a3;
}

// ---------------------------------------------------------------------------
// Agg1 + bias + relu + W2 projection, fused. One wave per node, lane=channel.
// h2[n][j] = sum_c relu( (A h1)[n][c] + b1[c] ) * W2[c][j]
// ---------------------------------------------------------------------------
__global__ __launch_bounds__(256) void k_agg1(const float* __restrict__ h1,
                                              const int* __restrict__ rp,
                                              const int* __restrict__ col,
                                              const float* __restrict__ dinv,
                                              const float* __restrict__ b1,
                                              const float* __restrict__ W2,
                                              float* __restrict__ h2, int N) {
    int node = blockIdx.x * 4 + (threadIdx.x >> 6);
    int lane = threadIdx.x & 63;
    if (node >= N) return;
    float di = dinv[node];
    float acc = h1[(size_t)node * H1 + lane] * (di * di);   // self loop
    int e = rp[node], end = rp[node + 1];
    for (; e < end; ++e) {
        int s = col[e];
        float w = dinv[s] * di;
        acc = fmaf(h1[(size_t)s * H1 + lane], w, acc);
    }
    float v = fmaxf(acc + b1[lane], 0.f);
    float p0 = v * W2[lane * 2 + 0];
    float p1 = v * W2[lane * 2 + 1];
#pragma unroll
    for (int off = 32; off; off >>= 1) {
        p0 += __shfl_xor(p0, off, 64);
        p1 += __shfl_xor(p1, off, 64);
    }
    if (lane == 0) {
        h2[(size_t)node * 2 + 0] = p0;
        h2[(size_t)node * 2 + 1] = p1;
    }
}

// ---------------------------------------------------------------------------
// Agg2 + bias: out[n][j] = b2[j] + (A h2)[n][j]. One thread per node (2 ch).
// ---------------------------------------------------------------------------
__global__ __launch_bounds__(256) void k_agg2(const float* __restrict__ h2,
                                              const int* __restrict__ rp,
                                              const int* __restrict__ col,
                                              const float* __restrict__ dinv,
                                              const float* __restrict__ b2,
                                              float* __restrict__ out, int N) {
    int n = blockIdx.x * blockDim.x + threadIdx.x;
    if (n >= N) return;
    float di = dinv[n];
    float a0 = h2[(size_t)n * 2 + 0] * (di * di);
    float a1 = h2[(size_t)n * 2 + 1] * (di * di);
    int e = rp[n], end = rp[n + 1];
    for (; e < end; ++e) {
        int s = col[e];
        float w = dinv[s] * di;
        a0 = fmaf(h2[(size_t)s * 2 + 0], w, a0);
        a1 = fmaf(h2[(size_t)s * 2 + 1], w, a1);
    }
    out[(size_t)n * 2 + 0] = a0 + b2[0];
    out[(size_t)n * 2 + 1] = a1 + b2[1];
}

// ---------------------------------------------------------------------------
extern "C" void kernel_launch(void* const* d_in, const int* in_sizes, int n_in,
                              void* d_out, int out_size, void* d_ws, size_t ws_size,
                              hipStream_t stream) {
    const float* x  = (const float*)d_in[0];
    const void*  E  = d_in[1];
    const float* W1 = (const float*)d_in[2];
    const float* b1 = (const float*)d_in[3];
    const float* W2 = (const float*)d_in[4];
    const float* b2 = (const float*)d_in[5];
    float* out = (float*)d_out;

    const int N  = in_sizes[0] / N_FEAT;   // 100000
    const int nE = in_sizes[1] / 2;        // 3200000

    char* ws = (char*)d_ws;
    size_t off = 0;
    auto alloc = [&](size_t bytes) -> void* {
        void* p = ws + off;
        off = (off + bytes + 255) & ~(size_t)255;
        return p;
    };
    int*   counts = (int*)alloc((size_t)N * 4);
    int*   cur    = (int*)alloc((size_t)N * 4);
    int*   rp     = (int*)alloc((size_t)(N + 1) * 4);
    int*   bsum   = (int*)alloc(4096);
    float* dinv   = (float*)alloc((size_t)N * 4);
    int*   flag   = (int*)alloc(256);
    int*   col    = (int*)alloc((size_t)nE * 4);
    float* h1     = (float*)alloc((size_t)N * H1 * 4);
    float* h2     = (float*)alloc((size_t)N * H2 * 4);

    hipMemsetAsync(counts, 0, (size_t)N * 4, stream);
    hipMemsetAsync(cur,    0, (size_t)N * 4, stream);

    const int egrid = (nE + 255) / 256;
    const int nb    = (N + 255) / 256;

    k_detect<<<1, 64, 0, stream>>>((const unsigned long long*)E, flag);
    k_count<<<egrid, 256, 0, stream>>>(E, (size_t)nE, flag, counts);
    k_scan_block<<<nb, 256, 0, stream>>>(counts, rp, bsum, N);
    k_scan_top<<<1, 512, 0, stream>>>(bsum, nb);
    k_scan_add<<<nb, 256, 0, stream>>>(rp, bsum, counts, dinv, N, nE);
    k_fill<<<egrid, 256, 0, stream>>>(E, (size_t)nE, flag, rp, cur, col);
    k_gemm1<<<(N + 15) / 16, 256, 0, stream>>>(x, W1, h1, N);
    k_agg1<<<(N + 3) / 4, 256, 0, stream>>>(h1, rp, col, dinv, b1, W2, h2, N);
    k_agg2<<<nb, 256, 0, stream>>>(h2, rp, col, dinv, b2, out, N);
}

// Round 2
// 727.439 us; speedup vs baseline: 1.2159x; 1.2159x over previous
//
#include <hip/hip_runtime.h>
#include <hip/hip_bf16.h>
#include <math.h>

#define N_FEAT 128
#define H1 64
#define H2 2

// ---------------------------------------------------------------------------
// Edge-index width detection: reference says int64, but JAX without x64 gives
// int32. Values < 1e6, so int32 pairs read as u64 are huge. Uniform per call.
// ---------------------------------------------------------------------------
__global__ void k_detect(const unsigned long long* __restrict__ E, int* __restrict__ flag) {
    if (threadIdx.x == 0 && blockIdx.x == 0) {
        int ok = 1;
        for (int i = 0; i < 16; ++i) {
            if (E[i] > 1000000ULL) { ok = 0; break; }
        }
        *flag = ok;  // 1 = int64, 0 = int32
    }
}

__device__ __forceinline__ int load_idx(const void* E, size_t i, int is64) {
    if (is64) return (int)((const long long*)E)[i];
    return ((const int*)E)[i];
}

// ---------------------------------------------------------------------------
// Histogram of dst (in-degree, excluding self loop)
// ---------------------------------------------------------------------------
__global__ void k_count(const void* __restrict__ E, size_t nE,
                        const int* __restrict__ flag, int* __restrict__ counts) {
    int is64 = *flag;
    size_t i = (size_t)blockIdx.x * blockDim.x + threadIdx.x;
    if (i < nE) {
        int d = load_idx(E, nE + i, is64);
        atomicAdd(&counts[d], 1);
    }
}

// ---------------------------------------------------------------------------
// Exclusive scan of counts -> rp
// ---------------------------------------------------------------------------
__global__ void k_scan_block(const int* __restrict__ counts, int* __restrict__ rp,
                             int* __restrict__ bsum, int N) {
    int i = blockIdx.x * 256 + threadIdx.x;
    int c = (i < N) ? counts[i] : 0;
    int lane = threadIdx.x & 63, wv = threadIdx.x >> 6;
    int v = c;
#pragma unroll
    for (int off = 1; off < 64; off <<= 1) {
        int t = __shfl_up(v, off, 64);
        if (lane >= off) v += t;
    }
    __shared__ int wsums[4];
    if (lane == 63) wsums[wv] = v;
    __syncthreads();
    int add = 0;
    for (int w = 0; w < wv; ++w) add += wsums[w];
    int incl = v + add;
    if (i < N) rp[i] = incl - c;               // exclusive within block
    if (threadIdx.x == 255) bsum[blockIdx.x] = incl;
}

__global__ void k_scan_top(int* __restrict__ bsum, int nb) {
    __shared__ int s[512];
    int t = threadIdx.x;
    int own = (t < nb) ? bsum[t] : 0;
    s[t] = own;
    __syncthreads();
    for (int off = 1; off < 512; off <<= 1) {
        int v = (t >= off) ? s[t - off] : 0;
        __syncthreads();
        s[t] += v;
        __syncthreads();
    }
    if (t < nb) bsum[t] = s[t] - own;          // exclusive block offsets
}

// rp finalize + cur init (= rp, so k_fill needs only one atomic) + dinv
__global__ void k_scan_add(int* __restrict__ rp, const int* __restrict__ bsum,
                           const int* __restrict__ counts, int* __restrict__ cur,
                           float* __restrict__ dinv, int N, int nE) {
    int i = blockIdx.x * 256 + threadIdx.x;
    if (i < N) {
        int v = rp[i] + bsum[i >> 8];
        rp[i] = v;
        cur[i] = v;
        dinv[i] = rsqrtf((float)(counts[i] + 1));   // +1 self loop
    }
    if (i == 0 && blockIdx.x == 0) rp[N] = nE;
}

// ---------------------------------------------------------------------------
// CSR fill: col[pos] = src, grouped by dst. cur pre-initialized to rp.
// ---------------------------------------------------------------------------
__global__ void k_fill(const void* __restrict__ E, size_t nE, const int* __restrict__ flag,
                       int* __restrict__ cur, int* __restrict__ col) {
    int is64 = *flag;
    size_t i = (size_t)blockIdx.x * blockDim.x + threadIdx.x;
    if (i < nE) {
        int s = load_idx(E, i, is64);
        int d = load_idx(E, nE + i, is64);
        int pos = atomicAdd(&cur[d], 1);
        col[pos] = s;
    }
}

// ---------------------------------------------------------------------------
// GEMM1: h1s = (x @ W1) * dinv[row]   [N,128]@[128,64], fp32. W1 in LDS.
// Pre-scaling by dinv[row] removes the per-edge dinv gather in k_agg1.
// ---------------------------------------------------------------------------
__global__ __launch_bounds__(256) void k_gemm1(const float* __restrict__ x,
                                               const float* __restrict__ W1,
                                               const float* __restrict__ dinv,
                                               float* __restrict__ h1s, int N) {
    __shared__ float Ws[N_FEAT * H1];
    for (int t = threadIdx.x; t < N_FEAT * H1; t += 256) Ws[t] = W1[t];
    __syncthreads();
    int lane = threadIdx.x & 63;
    int wv = threadIdx.x >> 6;
    int row0 = blockIdx.x * 16 + wv * 4;
    if (row0 >= N) return;
    int r0 = row0, r1 = min(row0 + 1, N - 1), r2 = min(row0 + 2, N - 1), r3 = min(row0 + 3, N - 1);
    const float* x0 = x + (size_t)r0 * N_FEAT;
    const float* x1 = x + (size_t)r1 * N_FEAT;
    const float* x2 = x + (size_t)r2 * N_FEAT;
    const float* x3 = x + (size_t)r3 * N_FEAT;
    float a0 = 0.f, a1 = 0.f, a2 = 0.f, a3 = 0.f;
#pragma unroll 8
    for (int k = 0; k < N_FEAT; ++k) {
        float w = Ws[k * H1 + lane];
        a0 = fmaf(x0[k], w, a0);
        a1 = fmaf(x1[k], w, a1);
        a2 = fmaf(x2[k], w, a2);
        a3 = fmaf(x3[k], w, a3);
    }
    if (row0 + 0 < N) h1s[(size_t)(row0 + 0) * H1 + lane] = a0 * dinv[r0];
    if (row0 + 1 < N) h1s[(size_t)(row0 + 1) * H1 + lane] = a1 * dinv[r1];
    if (row0 + 2 < N) h1s[(size_t)(row0 + 2) * H1 + lane] = a2 * dinv[r2];
    if (row0 + 3 < N) h1s[(size_t)(row0 + 3) * H1 + lane] = a3 * dinv[r3];
}

// ---------------------------------------------------------------------------
// Agg1 + bias + relu + W2 proj, fused. One wave per node, lane = channel.
// sum = h1s[node] + sum_e h1s[col[e]]  (pure gather — no per-edge dinv)
// v = relu(di*sum + b1); h2s[node] = di * (v @ W2)
// Edge loop unrolled x4: 4 independent 256B row-gathers in flight per wave.
// ---------------------------------------------------------------------------
__global__ __launch_bounds__(256) void k_agg1(const float* __restrict__ h1s,
                                              const int* __restrict__ rp,
                                              const int* __restrict__ col,
                                              const float* __restrict__ dinv,
                                              const float* __restrict__ b1,
                                              const float* __restrict__ W2,
                                              float2* __restrict__ h2s, int N) {
    int node = blockIdx.x * 4 + (threadIdx.x >> 6);
    int lane = threadIdx.x & 63;
    if (node >= N) return;
    float sum = h1s[(size_t)node * H1 + lane];      // self loop (pre-scaled)
    int e = rp[node], end = rp[node + 1];
    int elim = e + ((end - e) & ~3);
    for (; e < elim; e += 4) {
        int s0 = col[e + 0];
        int s1 = col[e + 1];
        int s2 = col[e + 2];
        int s3 = col[e + 3];
        float v0 = h1s[(size_t)s0 * H1 + lane];
        float v1 = h1s[(size_t)s1 * H1 + lane];
        float v2 = h1s[(size_t)s2 * H1 + lane];
        float v3 = h1s[(size_t)s3 * H1 + lane];
        sum += v0 + v1 + v2 + v3;
    }
    for (; e < end; ++e) sum += h1s[(size_t)col[e] * H1 + lane];

    float di = dinv[node];
    float v = fmaxf(fmaf(di, sum, b1[lane]), 0.f);
    float2 w2 = ((const float2*)W2)[lane];
    float p0 = v * w2.x;
    float p1 = v * w2.y;
#pragma unroll
    for (int off = 32; off; off >>= 1) {
        p0 += __shfl_xor(p0, off, 64);
        p1 += __shfl_xor(p1, off, 64);
    }
    if (lane == 0) h2s[node] = make_float2(di * p0, di * p1);
}

// ---------------------------------------------------------------------------
// Agg2 + bias: out[n] = di*(h2s[n] + sum_e h2s[col[e]]) + b2.
// 16-lane group per node: edge-parallel gathers + shuffle reduce.
// ---------------------------------------------------------------------------
__global__ __launch_bounds__(256) void k_agg2(const float2* __restrict__ h2s,
                                              const int* __restrict__ rp,
                                              const int* __restrict__ col,
                                              const float* __restrict__ dinv,
                                              const float* __restrict__ b2,
                                              float2* __restrict__ out, int N) {
    int g = threadIdx.x >> 4;
    int lane = threadIdx.x & 15;
    int node = blockIdx.x * 16 + g;
    if (node >= N) return;
    int e0 = rp[node], e1 = rp[node + 1];
    float a0 = 0.f, a1 = 0.f;
    for (int e = e0 + lane; e < e1; e += 16) {
        float2 v = h2s[col[e]];
        a0 += v.x;
        a1 += v.y;
    }
#pragma unroll
    for (int off = 8; off; off >>= 1) {
        a0 += __shfl_xor(a0, off, 16);
        a1 += __shfl_xor(a1, off, 16);
    }
    if (lane == 0) {
        float di = dinv[node];
        float2 self = h2s[node];
        out[node] = make_float2(fmaf(di, a0 + self.x, b2[0]),
                                fmaf(di, a1 + self.y, b2[1]));
    }
}

// ---------------------------------------------------------------------------
extern "C" void kernel_launch(void* const* d_in, const int* in_sizes, int n_in,
                              void* d_out, int out_size, void* d_ws, size_t ws_size,
                              hipStream_t stream) {
    const float* x  = (const float*)d_in[0];
    const void*  E  = d_in[1];
    const float* W1 = (const float*)d_in[2];
    const float* b1 = (const float*)d_in[3];
    const float* W2 = (const float*)d_in[4];
    const float* b2 = (const float*)d_in[5];
    float2* out = (float2*)d_out;

    const int N  = in_sizes[0] / N_FEAT;   // 100000
    const int nE = in_sizes[1] / 2;        // 3200000

    char* ws = (char*)d_ws;
    size_t off = 0;
    auto alloc = [&](size_t bytes) -> void* {
        void* p = ws + off;
        off = (off + bytes + 255) & ~(size_t)255;
        return p;
    };
    int*    counts = (int*)alloc((size_t)N * 4);
    int*    cur    = (int*)alloc((size_t)N * 4);
    int*    rp     = (int*)alloc((size_t)(N + 1) * 4);
    int*    bsum   = (int*)alloc(4096);
    float*  dinv   = (float*)alloc((size_t)N * 4);
    int*    flag   = (int*)alloc(256);
    int*    col    = (int*)alloc((size_t)nE * 4);
    float*  h1s    = (float*)alloc((size_t)N * H1 * 4);
    float2* h2s    = (float2*)alloc((size_t)N * 8);

    hipMemsetAsync(counts, 0, (size_t)N * 4, stream);

    const int egrid = (nE + 255) / 256;
    const int nb    = (N + 255) / 256;

    k_detect<<<1, 64, 0, stream>>>((const unsigned long long*)E, flag);
    k_count<<<egrid, 256, 0, stream>>>(E, (size_t)nE, flag, counts);
    k_scan_block<<<nb, 256, 0, stream>>>(counts, rp, bsum, N);
    k_scan_top<<<1, 512, 0, stream>>>(bsum, nb);
    k_scan_add<<<nb, 256, 0, stream>>>(rp, bsum, counts, cur, dinv, N, nE);
    k_fill<<<egrid, 256, 0, stream>>>(E, (size_t)nE, flag, cur, col);
    k_gemm1<<<(N + 15) / 16, 256, 0, stream>>>(x, W1, dinv, h1s, N);
    k_agg1<<<(N + 3) / 4, 256, 0, stream>>>(h1s, rp, col, dinv, b1, W2, h2s, N);
    k_agg2<<<(N + 15) / 16, 256, 0, stream>>>(h2s, rp, col, dinv, b2, out, N);
}